// Round 5
// baseline (537.411 us; speedup 1.0000x reference)
//
#include <hip/hip_runtime.h>
#include <hip/hip_bf16.h>
#include <cstdint>
#include <cstddef>

#define B_   32
#define S_   2048
#define DH_  1024
#define DF_  1024
#define DM_  512
#define MTOT (B_ * S_)   // 65536
#define NT_  (DF_ / 32)  // 32 K-tiles of BK=32

typedef __attribute__((ext_vector_type(8))) short bf16x8;
typedef __attribute__((ext_vector_type(4))) float f32x4;

#define AS1 __attribute__((address_space(1)))
#define AS3 __attribute__((address_space(3)))

static __device__ __forceinline__ void load_lds16(const void* g, void* l) {
    __builtin_amdgcn_global_load_lds((const AS1 unsigned*)g, (AS3 unsigned*)l,
                                     16, 0, 0);
}

// fp32 pair -> packed bf16, round-half-up (cheap)
static __device__ __forceinline__ unsigned pack_rhu(float a, float b) {
    unsigned ua = (__float_as_uint(a) + 0x8000u) >> 16;
    unsigned ub = (__float_as_uint(b) + 0x8000u) & 0xFFFF0000u;
    return ua | ub;
}

static __device__ __forceinline__ float tanh_fast(float x) {
    float e = __expf(2.0f * x);
    return 1.0f - 2.0f / (e + 1.0f);
}

static __device__ __forceinline__ float bflo(unsigned v) {
    return __uint_as_float(v << 16);
}
static __device__ __forceinline__ float bfhi(unsigned v) {
    return __uint_as_float(v & 0xFFFF0000u);
}

// ---------------------------------------------------------------------------
// embh[b][m] = dot(hidden[b], W1h[m]) + b1h[m] + b1f[m]
// 64 blocks x 8 rows; W-row fragments in regs; loop b over L2-resident hidden.
// W1h read exactly once (2 MB) vs 32x in the old grid.
// ---------------------------------------------------------------------------
__global__ __launch_bounds__(256) void k_embh(
    const float* __restrict__ hidden, const float* __restrict__ W1h,
    const float* __restrict__ b1h, const float* __restrict__ b1f,
    float* __restrict__ embh)
{
    int t    = threadIdx.x;
    int w    = t >> 6;          // 0..3
    int lane = t & 63;
    int m0   = blockIdx.x * 8 + w * 2;   // this wave: rows m0, m0+1

    // W rows in regs: 4 chunks of float4 at k = c*256 + lane*4
    float4 wr0[4], wr1[4];
    #pragma unroll
    for (int c = 0; c < 4; ++c) {
        wr0[c] = *(const float4*)(W1h + (size_t)m0 * DH_ + c * 256 + lane * 4);
        wr1[c] = *(const float4*)(W1h + (size_t)(m0 + 1) * DH_ + c * 256 + lane * 4);
    }
    float bias0 = b1h[m0] + b1f[m0];
    float bias1 = b1h[m0 + 1] + b1f[m0 + 1];

    for (int b = 0; b < B_; ++b) {
        float s0 = 0.0f, s1 = 0.0f;
        #pragma unroll
        for (int c = 0; c < 4; ++c) {
            float4 h = *(const float4*)(hidden + (size_t)b * DH_ + c * 256 + lane * 4);
            s0 += h.x * wr0[c].x + h.y * wr0[c].y + h.z * wr0[c].z + h.w * wr0[c].w;
            s1 += h.x * wr1[c].x + h.y * wr1[c].y + h.z * wr1[c].z + h.w * wr1[c].w;
        }
        #pragma unroll
        for (int off = 1; off < 64; off <<= 1) {
            s0 += __shfl_xor(s0, off);
            s1 += __shfl_xor(s1, off);
        }
        if (lane == 0) {
            embh[b * DM_ + m0]     = s0 + bias0;
            embh[b * DM_ + m0 + 1] = s1 + bias1;
        }
    }
}

// ---------------------------------------------------------------------------
// fp32 -> bf16 streaming convert for BOTH W1f and feats in one launch.
// Grid-stride over n4W + n4F float4s.
// ---------------------------------------------------------------------------
__global__ __launch_bounds__(256) void k_cvt2(
    const float* __restrict__ srcW, unsigned short* __restrict__ dstW, long n4W,
    const float* __restrict__ srcF, unsigned short* __restrict__ dstF, long n4F)
{
    long stride = (long)gridDim.x * 256;
    long ntot = n4W + n4F;
    for (long i = (long)blockIdx.x * 256 + threadIdx.x; i < ntot; i += stride) {
        const float4* s;
        uint2* d;
        long j;
        if (i < n4W) { s = (const float4*)srcW; d = (uint2*)dstW; j = i; }
        else         { s = (const float4*)srcF; d = (uint2*)dstF; j = i - n4W; }
        float4 a = s[j];
        uint2 r;
        r.x = pack_rhu(a.x, a.y);
        r.y = pack_rhu(a.z, a.w);
        d[j] = r;
    }
}

// ---------------------------------------------------------------------------
// MAIN GEMM — 256x256 tile, 8 waves (2M x 4N), BK=32, 16x16x32 bf16 MFMA.
// EXACT R2-verified body (dynamic buffer indices): 4 LDS buffers, depth-3
// prefetch, steady-state vmcnt(8); 2 phases/K-tile with
// {ds_read | stage ; bar ; lgkm ; setprio1 16xMFMA setprio0 ; bar}.
// LDS swizzle both-sides involution; grid 512 XCD-swizzled.
// ---------------------------------------------------------------------------
__global__ __launch_bounds__(512, 2) void k_gemm_bf(
    const unsigned short* __restrict__ fb, const unsigned short* __restrict__ wb,
    const float* __restrict__ embh, const float* __restrict__ w2,
    float* __restrict__ plog)
{
    __shared__ bf16x8 As[4][1024];   // 4 x 16 KB
    __shared__ bf16x8 Bs[4][1024];   // 4 x 16 KB

    const int t    = threadIdx.x;
    const int lane = t & 63;
    const int w    = t >> 6;        // 0..7
    const int wm   = w >> 2;        // 0..1 : 128-row group
    const int wn   = w & 3;         // 0..3 : 64-col group
    const int quad = lane >> 4;
    const int l16  = lane & 15;

    // XCD swizzle: pair (by,bx=0/1) -> same XCD slot (g mod 8)
    const int g    = blockIdx.x;               // 0..511
    const int flat = (g & 7) * 64 + (g >> 3);
    const int by   = flat >> 1;                // 0..255
    const int bx   = flat & 1;                 // 0..1

    // staging source (pre-swizzled chunk; lane-pure since base rows are %8==0)
    const int swz = ((lane & 3) ^ ((lane >> 3) & 3)) * 8;
    const unsigned short* srcA =
        fb + ((size_t)(by * 256 + w * 32 + (lane >> 2))) * DF_ + swz;
    const unsigned short* srcB =
        wb + ((size_t)(bx * 256 + w * 32 + (lane >> 2))) * DF_ + swz;

    f32x4 acc[8][4];
    const f32x4 zero = {0.0f, 0.0f, 0.0f, 0.0f};
    #pragma unroll
    for (int i = 0; i < 8; ++i)
        #pragma unroll
        for (int j = 0; j < 4; ++j) acc[i][j] = zero;

    // one K-tile of A (or B) staging: 2 x global_load_lds per wave
    auto stageA = [&](int kt) {
        load_lds16(srcA + kt * 32,            &As[kt & 3][(w * 2) * 64]);
        load_lds16(srcA + 16 * DF_ + kt * 32, &As[kt & 3][(w * 2 + 1) * 64]);
    };
    auto stageB = [&](int kt) {
        load_lds16(srcB + kt * 32,            &Bs[kt & 3][(w * 2) * 64]);
        load_lds16(srcB + 16 * DF_ + kt * 32, &Bs[kt & 3][(w * 2 + 1) * 64]);
    };

    // prologue: tiles 0,1,2 in flight (12 loads; order [A,A,B,B] per tile)
    stageA(0); stageB(0);
    stageA(1); stageB(1);
    stageA(2); stageB(2);

    const int sw4 = quad ^ ((l16 >> 1) & 3);
    const int sa  = (wm * 128 + l16) * 4 + sw4;
    const int sb  = (wn * 64 + l16) * 4 + sw4;

    for (int kt = 0; kt < NT_; ++kt) {
        const int buf = kt & 3;
        // retire THIS tile's 4 loads; keep kt+1/kt+2 (8) in flight
        if (kt < NT_ - 2)       asm volatile("s_waitcnt vmcnt(8)" ::: "memory");
        else if (kt == NT_ - 2) asm volatile("s_waitcnt vmcnt(4)" ::: "memory");
        else                    asm volatile("s_waitcnt vmcnt(0)" ::: "memory");
        __builtin_amdgcn_s_barrier();

        bf16x8 af[4], bfr[4];
        // ---- phase 0: mi 0..3 ----
        #pragma unroll
        for (int nj = 0; nj < 4; ++nj) bfr[nj] = Bs[buf][sb + nj * 64];
        #pragma unroll
        for (int mi = 0; mi < 4; ++mi) af[mi] = As[buf][sa + mi * 64];
        if (kt < NT_ - 3) stageA(kt + 3);
        __builtin_amdgcn_s_barrier();
        asm volatile("s_waitcnt lgkmcnt(0)" ::: "memory");
        __builtin_amdgcn_sched_barrier(0);
        __builtin_amdgcn_s_setprio(1);
        #pragma unroll
        for (int mi = 0; mi < 4; ++mi)
            #pragma unroll
            for (int nj = 0; nj < 4; ++nj)
                acc[mi][nj] = __builtin_amdgcn_mfma_f32_16x16x32_bf16(
                    af[mi], bfr[nj], acc[mi][nj], 0, 0, 0);
        __builtin_amdgcn_s_setprio(0);
        __builtin_amdgcn_s_barrier();

        // ---- phase 1: mi 4..7 ----
        #pragma unroll
        for (int mi = 0; mi < 4; ++mi) af[mi] = As[buf][sa + 256 + mi * 64];
        if (kt < NT_ - 3) stageB(kt + 3);
        __builtin_amdgcn_s_barrier();
        asm volatile("s_waitcnt lgkmcnt(0)" ::: "memory");
        __builtin_amdgcn_sched_barrier(0);
        __builtin_amdgcn_s_setprio(1);
        #pragma unroll
        for (int mi = 0; mi < 4; ++mi)
            #pragma unroll
            for (int nj = 0; nj < 4; ++nj)
                acc[4 + mi][nj] = __builtin_amdgcn_mfma_f32_16x16x32_bf16(
                    af[mi], bfr[nj], acc[4 + mi][nj], 0, 0, 0);
        __builtin_amdgcn_s_setprio(0);
        // phase-1 close barrier = next tile's post-vmcnt barrier
    }

    // epilogue: C/D layout col=l16 (b-side), row=quad*4+reg (a-side) — proven
    const int bIdx = by >> 3;
    float ew[4], wv[4];
    #pragma unroll
    for (int nj = 0; nj < 4; ++nj) {
        int c = bx * 256 + wn * 64 + nj * 16 + l16;
        ew[nj] = embh[bIdx * DM_ + c];
        wv[nj] = w2[c];
    }
    float* plw = plog + (size_t)(bx * 4 + wn) * MTOT + bIdx * S_;
    const int rbase = (by * 256 + wm * 128) & (S_ - 1);
    #pragma unroll
    for (int mi = 0; mi < 8; ++mi) {
        #pragma unroll
        for (int reg = 0; reg < 4; ++reg) {
            float p = 0.0f;
            #pragma unroll
            for (int nj = 0; nj < 4; ++nj)
                p += tanh_fast(acc[mi][nj][reg] + ew[nj]) * wv[nj];
            p += __shfl_xor(p, 1);
            p += __shfl_xor(p, 2);
            p += __shfl_xor(p, 4);
            p += __shfl_xor(p, 8);
            if (l16 == 0)
                plw[rbase + mi * 16 + quad * 4 + reg] = p;
        }
    }
}

// ---------------------------------------------------------------------------
// FALLBACK GEMM (fp32 A, in-kernel cheap pack) — used only if ws too small.
// ---------------------------------------------------------------------------
__global__ __launch_bounds__(256) void k_gemm_f32(
    const float* __restrict__ feats, const unsigned short* __restrict__ w1fb,
    const float* __restrict__ embh, const float* __restrict__ w2,
    float* __restrict__ plog)
{
    __shared__ bf16x8 As[4 * 128];
    __shared__ bf16x8 Bs[4 * 128];

    const int t    = threadIdx.x;
    const int lane = t & 63;
    const int w    = t >> 6;
    const int wm   = w >> 1;
    const int wn   = w & 1;
    const int quad = lane >> 4;
    const int l16  = lane & 15;
    const int blk   = blockIdx.x;
    const int panel = blk >> 5;
    const int sub   = blk & 31;
    const int bx    = sub >> 3;
    const int by    = panel * 8 + (sub & 7);

    const int sRow = t >> 1;
    const int sK   = (t & 1) * 16;
    const int c0   = sK >> 3;
    const float*          aG = feats + (size_t)(by * 128 + sRow) * DF_ + sK;
    const unsigned short* bG = w1fb  + (size_t)(bx * 128 + sRow) * DF_ + sK;

    f32x4 acc[4][4];
    const f32x4 zero = {0.0f, 0.0f, 0.0f, 0.0f};
    #pragma unroll
    for (int i = 0; i < 4; ++i)
        #pragma unroll
        for (int j = 0; j < 4; ++j) acc[i][j] = zero;

    for (int kt = 0; kt < DF_ / 32; ++kt) {
        float4 a0 = *(const float4*)(aG + kt * 32);
        float4 a1 = *(const float4*)(aG + kt * 32 + 4);
        float4 a2 = *(const float4*)(aG + kt * 32 + 8);
        float4 a3 = *(const float4*)(aG + kt * 32 + 12);
        uint4  b0 = *(const uint4*)(bG + kt * 32);
        uint4  b1 = *(const uint4*)(bG + kt * 32 + 8);

        __syncthreads();

        union { unsigned u[4]; bf16x8 v; } pa;
        pa.u[0] = pack_rhu(a0.x, a0.y);
        pa.u[1] = pack_rhu(a0.z, a0.w);
        pa.u[2] = pack_rhu(a1.x, a1.y);
        pa.u[3] = pack_rhu(a1.z, a1.w);
        As[c0 * 128 + sRow] = pa.v;
        pa.u[0] = pack_rhu(a2.x, a2.y);
        pa.u[1] = pack_rhu(a2.z, a2.w);
        pa.u[2] = pack_rhu(a3.x, a3.y);
        pa.u[3] = pack_rhu(a3.z, a3.w);
        As[(c0 + 1) * 128 + sRow] = pa.v;

        union { uint4 q; bf16x8 v; } pb;
        pb.q = b0;
        Bs[c0 * 128 + sRow] = pb.v;
        pb.q = b1;
        Bs[(c0 + 1) * 128 + sRow] = pb.v;

        __syncthreads();

        bf16x8 af[4], bfr[4];
        #pragma unroll
        for (int mi = 0; mi < 4; ++mi)
            af[mi] = As[quad * 128 + wm * 64 + mi * 16 + l16];
        #pragma unroll
        for (int nj = 0; nj < 4; ++nj)
            bfr[nj] = Bs[quad * 128 + wn * 64 + nj * 16 + l16];

        #pragma unroll
        for (int mi = 0; mi < 4; ++mi)
            #pragma unroll
            for (int nj = 0; nj < 4; ++nj)
                acc[mi][nj] = __builtin_amdgcn_mfma_f32_16x16x32_bf16(
                    af[mi], bfr[nj], acc[mi][nj], 0, 0, 0);
    }

    const int bIdx = by >> 4;
    float ew[4], wv[4];
    #pragma unroll
    for (int nj = 0; nj < 4; ++nj) {
        int c = bx * 128 + wn * 64 + nj * 16 + l16;
        ew[nj] = embh[bIdx * DM_ + c];
        wv[nj] = w2[c];
    }
    float* plw = plog + (size_t)(bx * 2 + wn) * MTOT + bIdx * S_;
    #pragma unroll
    for (int mi = 0; mi < 4; ++mi) {
        #pragma unroll
        for (int reg = 0; reg < 4; ++reg) {
            float p = 0.0f;
            #pragma unroll
            for (int nj = 0; nj < 4; ++nj)
                p += tanh_fast(acc[mi][nj][reg] + ew[nj]) * wv[nj];
            p += __shfl_xor(p, 1);
            p += __shfl_xor(p, 2);
            p += __shfl_xor(p, 4);
            p += __shfl_xor(p, 8);
            if (l16 == 0) {
                int rowl = wm * 64 + mi * 16 + quad * 4 + reg;
                int s = (by * 128 + rowl) & (S_ - 1);
                plw[s] = p;
            }
        }
    }
}

// ---------------------------------------------------------------------------
// combine 8 partials, softmax over S per batch row
// ---------------------------------------------------------------------------
__global__ __launch_bounds__(256) void k_softmax(
    const float* __restrict__ plog, float* __restrict__ probs_out)
{
    int b = blockIdx.x;
    int t = threadIdx.x;
    float l[8];
    #pragma unroll
    for (int i = 0; i < 8; ++i) {
        int s = t + i * 256;
        float sum = 0.0f;
        #pragma unroll
        for (int p = 0; p < 8; ++p)
            sum += plog[(size_t)p * MTOT + b * S_ + s];
        l[i] = sum;
    }
    float mx = l[0];
    #pragma unroll
    for (int i = 1; i < 8; ++i) mx = fmaxf(mx, l[i]);
    #pragma unroll
    for (int off = 1; off < 64; off <<= 1) mx = fmaxf(mx, __shfl_xor(mx, off));
    __shared__ float redm[4];
    __shared__ float reds[4];
    int wid = t >> 6;
    if ((t & 63) == 0) redm[wid] = mx;
    __syncthreads();
    mx = fmaxf(fmaxf(redm[0], redm[1]), fmaxf(redm[2], redm[3]));

    float e[8];
    float es = 0.0f;
    #pragma unroll
    for (int i = 0; i < 8; ++i) {
        e[i] = __expf(l[i] - mx);
        es += e[i];
    }
    #pragma unroll
    for (int off = 1; off < 64; off <<= 1) es += __shfl_xor(es, off);
    if ((t & 63) == 0) reds[wid] = es;
    __syncthreads();
    es = reds[0] + reds[1] + reds[2] + reds[3];
    float inv = 1.0f / es;
    #pragma unroll
    for (int i = 0; i < 8; ++i)
        probs_out[b * S_ + t + i * 256] = e[i] * inv;
}

// ---------------------------------------------------------------------------
// context partials (bf16 feats), 16B loads per lane.
//   grid (B_, 16), 256 threads. ctxp[(z*2+half)][b][d] -> 32 partials
// ---------------------------------------------------------------------------
__global__ __launch_bounds__(256) void k_context_bf(
    const unsigned short* __restrict__ fb, const float* __restrict__ probs,
    float* __restrict__ ctxp)
{
    int t    = threadIdx.x;
    int b    = blockIdx.x;
    int z    = blockIdx.y;        // 0..15
    int half = t >> 7;            // 0,1
    int dt   = t & 127;           // d/8
    int s0   = z * 128 + half * 64;

    const uint4* f  = (const uint4*)(fb + (size_t)(b * S_ + s0) * DF_) + dt;
    const float* pr = probs + b * S_ + s0;

    float acc[8];
    #pragma unroll
    for (int j = 0; j < 8; ++j) acc[j] = 0.0f;

    #pragma unroll 8
    for (int i = 0; i < 64; ++i) {
        uint4 v = f[(size_t)i * (DF_ / 8)];
        float p = pr[i];
        acc[0] += p * bflo(v.x);
        acc[1] += p * bfhi(v.x);
        acc[2] += p * bflo(v.y);
        acc[3] += p * bfhi(v.y);
        acc[4] += p * bflo(v.z);
        acc[5] += p * bfhi(v.z);
        acc[6] += p * bflo(v.w);
        acc[7] += p * bfhi(v.w);
    }

    float4* o = (float4*)(ctxp + ((size_t)(z * 2 + half) * B_ + b) * DF_ + dt * 8);
    o[0] = make_float4(acc[0], acc[1], acc[2], acc[3]);
    o[1] = make_float4(acc[4], acc[5], acc[6], acc[7]);
}

// fp32-feats fallback context (32 partials of 64 rows each)
__global__ __launch_bounds__(256) void k_context_f32(
    const float* __restrict__ feats, const float* __restrict__ probs,
    float* __restrict__ ctxp)
{
    int d  = blockIdx.x * 256 + threadIdx.x;
    int b  = blockIdx.y;
    int z  = blockIdx.z;          // 0..31
    const float* f  = feats + ((size_t)b * S_ + z * 64) * DF_ + d;
    const float* pr = probs + b * S_ + z * 64;
    float acc = 0.0f;
    #pragma unroll 4
    for (int i = 0; i < 64; ++i)
        acc += pr[i] * f[(size_t)i * DF_];
    ctxp[((size_t)z * B_ + b) * DF_ + d] = acc;
}

__global__ __launch_bounds__(256) void k_ctx_red(
    const float* __restrict__ ctxp, float* __restrict__ ctx)
{
    int i = blockIdx.x * 256 + threadIdx.x;
    float s = 0.0f;
    #pragma unroll
    for (int z = 0; z < 32; ++z)
        s += ctxp[(size_t)z * B_ * DF_ + i];
    ctx[i] = s;
}

// ---------------------------------------------------------------------------
extern "C" void kernel_launch(void* const* d_in, const int* in_sizes, int n_in,
                              void* d_out, int out_size, void* d_ws, size_t ws_size,
                              hipStream_t stream)
{
    const float* hidden = (const float*)d_in[0];
    const float* feats  = (const float*)d_in[1];
    const float* W1h    = (const float*)d_in[2];
    const float* b1h    = (const float*)d_in[3];
    const float* W1f    = (const float*)d_in[4];
    const float* b1f    = (const float*)d_in[5];
    const float* w2     = (const float*)d_in[6];

    float* out   = (float*)d_out;
    float* ctx   = out;              // [B, DF]   (output 0)
    float* probs = out + B_ * DF_;   // [B, 1, S] (output 1)

    char* ws = (char*)d_ws;
    float*          embh  = (float*)ws;                              // 64 KB
    unsigned short* w1fb  = (unsigned short*)(ws + (64 << 10));      // 1 MB
    float*          plog  = (float*)(ws + (64 << 10) + (1 << 20));   // 2 MB
    float*          ctxp  = (float*)(ws + (64 << 10) + (3 << 20));   // 4 MB
    unsigned short* featb = (unsigned short*)(ws + (8 << 20));       // 128 MB

    const bool big_ws = ws_size >= ((size_t)8 << 20) + ((size_t)B_ * S_ * DF_ * 2);

    k_embh<<<dim3(DM_ / 8), 256, 0, stream>>>(hidden, W1h, b1h, b1f, embh);

    if (big_ws) {
        k_cvt2<<<dim3(8192), 256, 0, stream>>>(
            W1f, w1fb, (long)DM_ * DF_ / 4, feats, featb, (long)MTOT * DF_ / 4);
        k_gemm_bf<<<dim3((MTOT / 256) * (DM_ / 256)), 512, 0, stream>>>(
            featb, w1fb, embh, w2, plog);
        k_softmax<<<dim3(B_), 256, 0, stream>>>(plog, probs);
        k_context_bf<<<dim3(B_, 16), 256, 0, stream>>>(featb, probs, ctxp);
    } else {
        k_cvt2<<<dim3(512), 256, 0, stream>>>(
            W1f, w1fb, (long)DM_ * DF_ / 4, W1f, w1fb, 0L);
        k_gemm_f32<<<dim3((MTOT / 128) * (DM_ / 128)), 256, 0, stream>>>(
            feats, w1fb, embh, w2, plog);
        k_softmax<<<dim3(B_), 256, 0, stream>>>(plog, probs);
        k_context_f32<<<dim3(DF_ / 256, B_, 32), 256, 0, stream>>>(feats, probs, ctxp);
    }
    k_ctx_red<<<dim3(B_ * DF_ / 256), 256, 0, stream>>>(ctxp, ctx);
}